// Round 7
// baseline (337.848 us; speedup 1.0000x reference)
//
#include <hip/hip_runtime.h>
#include <math.h>

// ALiBi attention: B=2, T=2048, D=1024, H=16, hd=64. fp32 in/out.
// convert->bf16 -> QKV GEMM (BK=32, async-LDS staging) -> flash (one q-tile per
// block; long q-tiles split-K into 2 blocks, combinable because softmax uses a
// fixed offset instead of a running max) -> combine -> out proj GEMM.

#define T_SEQ 2048
#define DM    1024
#define NH    16
#define HD    64
#define NROW  4096   // B*T

typedef __attribute__((ext_vector_type(8))) short bf16x8;
typedef __attribute__((ext_vector_type(4))) short bf16x4;
typedef __attribute__((ext_vector_type(4))) float f32x4;

__device__ __forceinline__ short f2bf(float f) {
  unsigned u = __float_as_uint(f);
  u += 0x7FFFu + ((u >> 16) & 1u);
  return (short)(u >> 16);
}
__device__ __forceinline__ float bf2f(short s) {
  return __uint_as_float(((unsigned)(unsigned short)s) << 16);
}

// async global->LDS, 16B per lane; lds dest is wave-uniform base + lane*16B.
__device__ __forceinline__ void gload_lds16(short* lds, const short* g) {
  __builtin_amdgcn_global_load_lds((const __attribute__((address_space(1))) void*)g,
                                   (__attribute__((address_space(3))) void*)lds, 16, 0, 0);
}

// ---------------------------------------------------------------------------
// Merged fp32->bf16 conversion: x (4M) + 4 weights (1M each), 2M float4 groups.
// ---------------------------------------------------------------------------
__global__ __launch_bounds__(256) void convert_all(
    const float* __restrict__ x,  const float* __restrict__ wq,
    const float* __restrict__ wk, const float* __restrict__ wv,
    const float* __restrict__ wo,
    short* __restrict__ xb,  short* __restrict__ wqb, short* __restrict__ wkb,
    short* __restrict__ wvb, short* __restrict__ wob) {
  const int i = blockIdx.x * 256 + threadIdx.x;
  const float* s; short* d; int off;
  if (i < (1 << 20)) { s = x; d = xb; off = i; }
  else {
    const int j = i - (1 << 20);
    const int w = j >> 18;
    off = j & ((1 << 18) - 1);
    s = (w == 0) ? wq : (w == 1) ? wk : (w == 2) ? wv : wo;
    d = (w == 0) ? wqb : (w == 1) ? wkb : (w == 2) ? wvb : wob;
  }
  const float4 v = ((const float4*)s)[off];
  bf16x4 o = {f2bf(v.x), f2bf(v.y), f2bf(v.z), f2bf(v.w)};
  *(bf16x4*)(d + 4 * (size_t)off) = o;
}

// ---------------------------------------------------------------------------
// GEMM: C[m][n] = sum_k A[m][k] * W[n][k]. 128x128 tile, BK=32 (round-5 proven),
// async global_load_lds staging into unpadded [128][32] LDS tiles.
// ---------------------------------------------------------------------------
template <typename OutT>
__device__ __forceinline__ void gemm_body(const short* __restrict__ A,
                                          const short* __restrict__ W,
                                          OutT* __restrict__ C) {
  __shared__ short sA[128][32];
  __shared__ short sB[128][32];
  const int tid  = threadIdx.x;
  const int lane = tid & 63, wv = tid >> 6;
  const int quad = lane >> 4, l16 = lane & 15;
  const int wm = (wv >> 1) * 64, wn = (wv & 1) * 64;
  const size_t m0 = (size_t)blockIdx.x * 128, n0 = (size_t)blockIdx.y * 128;

  f32x4 acc[4][4];
#pragma unroll
  for (int i = 0; i < 4; ++i)
#pragma unroll
    for (int j = 0; j < 4; ++j) acc[i][j] = (f32x4){0.f, 0.f, 0.f, 0.f};

  const int grow = lane >> 2;          // 0..15
  const int gcol = (lane & 3) << 3;    // 0,8,16,24

  for (int k0 = 0; k0 < DM; k0 += 32) {
    __syncthreads();
    {
      const short* ga = A + (m0 + wv * 32 + grow) * DM + k0 + gcol;
      gload_lds16(&sA[wv * 32][0],      ga);
      gload_lds16(&sA[wv * 32 + 16][0], ga + 16 * DM);
      const short* gb = W + (n0 + wv * 32 + grow) * DM + k0 + gcol;
      gload_lds16(&sB[wv * 32][0],      gb);
      gload_lds16(&sB[wv * 32 + 16][0], gb + 16 * DM);
    }
    __syncthreads();   // drains vmcnt before LDS reads

    bf16x8 af[4], bfr[4];
#pragma unroll
    for (int t = 0; t < 4; ++t) {
      af[t]  = *(const bf16x8*)&sA[wm + t * 16 + l16][quad * 8];
      bfr[t] = *(const bf16x8*)&sB[wn + t * 16 + l16][quad * 8];
    }
#pragma unroll
    for (int mt = 0; mt < 4; ++mt)
#pragma unroll
      for (int nt = 0; nt < 4; ++nt)
        acc[mt][nt] = __builtin_amdgcn_mfma_f32_16x16x32_bf16(af[mt], bfr[nt], acc[mt][nt], 0, 0, 0);
  }
#pragma unroll
  for (int mt = 0; mt < 4; ++mt) {
#pragma unroll
    for (int r = 0; r < 4; ++r) {
      const size_t m = m0 + wm + mt * 16 + quad * 4 + r;
      OutT* crow = C + m * DM;
#pragma unroll
      for (int nt = 0; nt < 4; ++nt) {
        const float v = acc[mt][nt][r];
        if constexpr (sizeof(OutT) == 2)
          crow[n0 + wn + nt * 16 + l16] = f2bf(v);
        else
          crow[n0 + wn + nt * 16 + l16] = v;
      }
    }
  }
}

__global__ __launch_bounds__(256) void gemm_qkv(
    const short* __restrict__ x,
    const short* __restrict__ Wq, const short* __restrict__ Wk, const short* __restrict__ Wv,
    short* __restrict__ Qb, short* __restrict__ Kb, short* __restrict__ Vb) {
  const short* W = (blockIdx.z == 0) ? Wq : (blockIdx.z == 1) ? Wk : Wv;
  short*       C = (blockIdx.z == 0) ? Qb : (blockIdx.z == 1) ? Kb : Vb;
  gemm_body<short>(x, W, C);
}

__global__ __launch_bounds__(256) void gemm_out(const short* __restrict__ A,
                                                const short* __restrict__ W,
                                                float* __restrict__ C) {
  gemm_body<float>(A, W, C);
}

// ---------------------------------------------------------------------------
// Flash attention, ALiBi, causal, fixed-offset softmax (exp2 domain, no max).
// Work item (blockIdx.x, 48 per (h,b)):
//   item 0..31 : qt = 16+(item>>1), half = item&1  (split-K over kv range)
//   item 32..47: qt = 47-item, full range          (qt 15..0)
// Split items write unnormalized bf16 O-partials + fp32 l-partials; full items
// normalize and store directly. Max per-block cost = 16 kv-tiles.
// ---------------------------------------------------------------------------
__global__ __launch_bounds__(256) void flash_alibi(const short* __restrict__ Q,
                                                   const short* __restrict__ K,
                                                   const short* __restrict__ V,
                                                   short* __restrict__ O,
                                                   short* __restrict__ Po,
                                                   float* __restrict__ Pl) {
  __shared__ short sK[64][72];            // [key][dim]
  __shared__ unsigned int sVt2[64][35];   // [dim][keypair]; 2-way = free
  __shared__ short sP[4][16][76];         // write banks all-distinct

  const int tid  = threadIdx.x;
  const int lane = tid & 63, wv = tid >> 6;
  const int quad = lane >> 4, l16 = lane & 15;
  const int item = blockIdx.x;
  int qt, half;
  if (item < 32) { qt = 16 + (item >> 1); half = item & 1; }
  else           { qt = 47 - item;        half = -1; }
  const int n = qt + 1;
  int kts, kte;
  if (half < 0) { kts = 0; kte = n; }
  else { const int n0 = n >> 1; kts = half ? n0 : 0; kte = half ? n : n0; }

  const int h = blockIdx.y, b = blockIdx.z;
  const size_t base = (size_t)b * T_SEQ * DM + (size_t)h * HD;
  const int qi_base = qt * 64;
  const int qi0 = qi_base + wv * 16;

  // Q fragments (A-layout: m=l16, k=quad*8+j)
  bf16x8 qf[2];
  {
    const short* qp = Q + base + (size_t)(qi0 + l16) * DM + quad * 8;
    qf[0] = *(const bf16x8*)(qp);
    qf[1] = *(const bf16x8*)(qp + 32);
  }

  const float L2E = 1.4426950408889634f;
  const float slope = exp2f(-0.5f * (float)(h + 1));
  const float sl2 = slope * L2E;
  const float SC = 0.125f * L2E;

  float kcol[4], qrow[4];
#pragma unroll
  for (int c = 0; c < 4; ++c) kcol[c] = sl2 * (float)(c * 16 + l16);
#pragma unroll
  for (int r = 0; r < 4; ++r)
    qrow[r] = sl2 * (float)(qi0 + quad * 4 + r) + 12.0f * L2E;

  f32x4 oacc[4];
#pragma unroll
  for (int c = 0; c < 4; ++c) oacc[c] = (f32x4){0.f, 0.f, 0.f, 0.f};
  float lpart[4] = {0.f, 0.f, 0.f, 0.f};

  const int srow = tid >> 3;
  const int scol = (tid & 7) << 3;
  const int kpair = tid >> 3;
  const int d0 = (tid & 7) << 3;

  for (int kt = kts; kt < kte; ++kt) {
    const int k0 = kt * 64;
    __syncthreads();   // protect sK/sVt2 from previous tile's readers
#pragma unroll
    for (int p = 0; p < 2; ++p) {
      const int row = srow + p * 32;
      *(bf16x8*)&sK[row][scol] = *(const bf16x8*)(K + base + (size_t)(k0 + row) * DM + scol);
    }
    {
      const short* v0 = V + base + (size_t)(k0 + 2 * kpair) * DM + d0;
      bf16x8 va = *(const bf16x8*)v0;
      bf16x8 vb = *(const bf16x8*)(v0 + DM);
#pragma unroll
      for (int e = 0; e < 8; ++e) {
        unsigned w = ((unsigned)(unsigned short)va[e]) |
                     (((unsigned)(unsigned short)vb[e]) << 16);
        sVt2[d0 + e][kpair] = w;
      }
    }
    __syncthreads();

    // S = Q K^T
    f32x4 sacc[4];
#pragma unroll
    for (int c = 0; c < 4; ++c) {
      f32x4 a = (f32x4){0.f, 0.f, 0.f, 0.f};
      a = __builtin_amdgcn_mfma_f32_16x16x32_bf16(
              qf[0], *(const bf16x8*)&sK[c * 16 + l16][quad * 8], a, 0, 0, 0);
      a = __builtin_amdgcn_mfma_f32_16x16x32_bf16(
              qf[1], *(const bf16x8*)&sK[c * 16 + l16][32 + quad * 8], a, 0, 0, 0);
      sacc[c] = a;
    }

    // softmax numerator (exp2 domain); mask only on the diagonal tile
    const float t0 = sl2 * (float)k0;
    const bool mask = (kt == qt);
#pragma unroll
    for (int c = 0; c < 4; ++c) {
      const float tc = t0 + kcol[c];
#pragma unroll
      for (int r = 0; r < 4; ++r) {
        float p = exp2f(fmaf(sacc[c][r], SC, tc - qrow[r]));
        if (mask) {
          const int kj = k0 + c * 16 + l16;
          const int qi = qi0 + quad * 4 + r;
          p = (kj <= qi) ? p : 0.0f;
        }
        lpart[r] += p;
        sP[wv][quad * 4 + r][c * 16 + l16] = (short)(__float_as_uint(p) >> 16);
      }
    }
    // sP is wave-private; in-wave LDS ordering handled by lgkmcnt.

    // O += P V
#pragma unroll
    for (int s = 0; s < 2; ++s) {
      bf16x8 pf = *(const bf16x8*)&sP[wv][l16][s * 32 + quad * 8];
#pragma unroll
      for (int c = 0; c < 4; ++c) {
        const unsigned* vp = &sVt2[c * 16 + l16][s * 16 + quad * 4];
        bf16x4 vlo = *(const bf16x4*)vp;
        bf16x4 vhi = *(const bf16x4*)(vp + 2);
        bf16x8 vf = {vlo[0], vlo[1], vlo[2], vlo[3], vhi[0], vhi[1], vhi[2], vhi[3]};
        oacc[c] = __builtin_amdgcn_mfma_f32_16x16x32_bf16(pf, vf, oacc[c], 0, 0, 0);
      }
    }
  }

  if (half < 0) {
    // full tile: normalize and store bf16
#pragma unroll
    for (int r = 0; r < 4; ++r) {
      float l = lpart[r];
#pragma unroll
      for (int off = 1; off < 16; off <<= 1) l += __shfl_xor(l, off);
      const float inv = 1.0f / fmaxf(l, 1e-37f);
      short* orow = O + base + (size_t)(qi0 + quad * 4 + r) * DM;
#pragma unroll
      for (int c = 0; c < 4; ++c)
        orow[c * 16 + l16] = f2bf(oacc[c][r] * inv);
    }
  } else {
    // split half: store unnormalized O partial (bf16) + l partial (fp32)
    const int pidx = (((b * NH + h) * 16) + (qt - 16)) * 2 + half;
    short* po = Po + (size_t)pidx * 4096;   // [64 rows][64 dims]
    float* pl = Pl + (size_t)pidx * 64;
#pragma unroll
    for (int r = 0; r < 4; ++r) {
      float l = lpart[r];
#pragma unroll
      for (int off = 1; off < 16; off <<= 1) l += __shfl_xor(l, off);
      const int row = wv * 16 + quad * 4 + r;
      if (l16 == 0) pl[row] = l;
#pragma unroll
      for (int c = 0; c < 4; ++c)
        po[row * 64 + c * 16 + l16] = f2bf(oacc[c][r]);
    }
  }
}

// ---------------------------------------------------------------------------
// Combine: for long rows, O = (O0+O1)/(l0+l1) -> bf16 into attention output.
// 32768 long rows x 64 dims; 32 rows/block, 8 threads/row.
// ---------------------------------------------------------------------------
__global__ __launch_bounds__(256) void combine(const short* __restrict__ Po,
                                               const float* __restrict__ Pl,
                                               short* __restrict__ O) {
  const int g = blockIdx.x * 32 + (threadIdx.x >> 3);   // 0..32767
  const int d = (threadIdx.x & 7) << 3;
  const int row = g & 63;
  const int lt  = (g >> 6) & 15;
  const int h   = (g >> 10) & 15;
  const int b   = g >> 14;
  const int pbase = (((b * NH + h) * 16) + lt) * 2;
  const short* p0 = Po + (size_t)(pbase + 0) * 4096 + row * 64 + d;
  const short* p1 = Po + (size_t)(pbase + 1) * 4096 + row * 64 + d;
  const float l = Pl[(pbase + 0) * 64 + row] + Pl[(pbase + 1) * 64 + row];
  const float inv = 1.0f / fmaxf(l, 1e-37f);
  bf16x8 a = *(const bf16x8*)p0;
  bf16x8 bb = *(const bf16x8*)p1;
  const int qi = (16 + lt) * 64 + row;
  short* orow = O + (size_t)b * T_SEQ * DM + (size_t)qi * DM + h * HD + d;
  bf16x8 o;
#pragma unroll
  for (int e = 0; e < 8; ++e) o[e] = f2bf((bf2f(a[e]) + bf2f(bb[e])) * inv);
  *(bf16x8*)orow = o;
}

// ---------------------------------------------------------------------------
extern "C" void kernel_launch(void* const* d_in, const int* in_sizes, int n_in,
                              void* d_out, int out_size, void* d_ws, size_t ws_size,
                              hipStream_t stream) {
  float* out = (float*)d_out;   // fp32 output

  short* ws = (short*)d_ws;
  const size_t plane = (size_t)NROW * DM;   // 4M elements
  const size_t wsz   = (size_t)DM * DM;     // 1M elements
  short* xb  = ws;
  short* Wqb = xb + plane;
  short* Wkb = Wqb + wsz;
  short* Wvb = Wkb + wsz;
  short* Wob = Wvb + wsz;
  short* Qb  = Wob + wsz;
  short* Kb  = Qb + plane;
  short* Vb  = Kb + plane;
  short* Ab  = Vb + plane;
  short* Po  = Ab + plane;                  // 1024 slabs * 4096 bf16 = 8 MB
  float* Pl  = (float*)(Po + (size_t)1024 * 4096);   // 64K floats

  dim3 blk(256);
  convert_all<<<8192, blk, 0, stream>>>(
      (const float*)d_in[0], (const float*)d_in[1], (const float*)d_in[2],
      (const float*)d_in[3], (const float*)d_in[4],
      xb, Wqb, Wkb, Wvb, Wob);

  gemm_qkv<<<dim3(NROW / 128, DM / 128, 3), blk, 0, stream>>>(xb, Wqb, Wkb, Wvb, Qb, Kb, Vb);
  flash_alibi<<<dim3(48, NH, 2), blk, 0, stream>>>(Qb, Kb, Vb, Ab, Po, Pl);
  combine<<<1024, blk, 0, stream>>>(Po, Pl, Ab);
  gemm_out<<<dim3(NROW / 128, DM / 128, 1), blk, 0, stream>>>(Ab, Wob, out);
}

// Round 8
// 205.950 us; speedup vs baseline: 1.6404x; 1.6404x over previous
//
#include <hip/hip_runtime.h>
#include <math.h>

// ALiBi attention: B=2, T=2048, D=1024, H=16, hd=64. fp32 in/out.
// Round 8 = bisect: round-5 flash inner loop VERBATIM + split-K mapping only.
// convert->bf16 -> QKV GEMM (BK=32 async-LDS) -> flash (split-K long tiles,
// fixed-offset softmax) -> combine -> out proj GEMM.

#define T_SEQ 2048
#define DM    1024
#define NH    16
#define HD    64
#define NROW  4096   // B*T

typedef __attribute__((ext_vector_type(8))) short bf16x8;
typedef __attribute__((ext_vector_type(4))) short bf16x4;
typedef __attribute__((ext_vector_type(4))) float f32x4;

__device__ __forceinline__ short f2bf(float f) {
  unsigned u = __float_as_uint(f);
  u += 0x7FFFu + ((u >> 16) & 1u);
  return (short)(u >> 16);
}
__device__ __forceinline__ float bf2f(short s) {
  return __uint_as_float(((unsigned)(unsigned short)s) << 16);
}

// async global->LDS, 16B per lane; lds dest is wave-uniform base + lane*16B.
__device__ __forceinline__ void gload_lds16(short* lds, const short* g) {
  __builtin_amdgcn_global_load_lds((const __attribute__((address_space(1))) void*)g,
                                   (__attribute__((address_space(3))) void*)lds, 16, 0, 0);
}

// ---------------------------------------------------------------------------
// Merged fp32->bf16 conversion: x (4M) + 4 weights (1M each), 2M float4 groups.
// ---------------------------------------------------------------------------
__global__ __launch_bounds__(256) void convert_all(
    const float* __restrict__ x,  const float* __restrict__ wq,
    const float* __restrict__ wk, const float* __restrict__ wv,
    const float* __restrict__ wo,
    short* __restrict__ xb,  short* __restrict__ wqb, short* __restrict__ wkb,
    short* __restrict__ wvb, short* __restrict__ wob) {
  const int i = blockIdx.x * 256 + threadIdx.x;
  const float* s; short* d; int off;
  if (i < (1 << 20)) { s = x; d = xb; off = i; }
  else {
    const int j = i - (1 << 20);
    const int w = j >> 18;
    off = j & ((1 << 18) - 1);
    s = (w == 0) ? wq : (w == 1) ? wk : (w == 2) ? wv : wo;
    d = (w == 0) ? wqb : (w == 1) ? wkb : (w == 2) ? wvb : wob;
  }
  const float4 v = ((const float4*)s)[off];
  bf16x4 o = {f2bf(v.x), f2bf(v.y), f2bf(v.z), f2bf(v.w)};
  *(bf16x4*)(d + 4 * (size_t)off) = o;
}

// ---------------------------------------------------------------------------
// GEMM (round-5 exact): C[m][n] = sum_k A[m][k]*W[n][k]. 128x128, BK=32.
// ---------------------------------------------------------------------------
template <typename OutT>
__device__ __forceinline__ void gemm_body(const short* __restrict__ A,
                                          const short* __restrict__ W,
                                          OutT* __restrict__ C) {
  __shared__ short sA[128][32];
  __shared__ short sB[128][32];
  const int tid  = threadIdx.x;
  const int lane = tid & 63, wv = tid >> 6;
  const int quad = lane >> 4, l16 = lane & 15;
  const int wm = (wv >> 1) * 64, wn = (wv & 1) * 64;
  const size_t m0 = (size_t)blockIdx.x * 128, n0 = (size_t)blockIdx.y * 128;

  f32x4 acc[4][4];
#pragma unroll
  for (int i = 0; i < 4; ++i)
#pragma unroll
    for (int j = 0; j < 4; ++j) acc[i][j] = (f32x4){0.f, 0.f, 0.f, 0.f};

  const int grow = lane >> 2;
  const int gcol = (lane & 3) << 3;

  for (int k0 = 0; k0 < DM; k0 += 32) {
    __syncthreads();
    {
      const short* ga = A + (m0 + wv * 32 + grow) * DM + k0 + gcol;
      gload_lds16(&sA[wv * 32][0],      ga);
      gload_lds16(&sA[wv * 32 + 16][0], ga + 16 * DM);
      const short* gb = W + (n0 + wv * 32 + grow) * DM + k0 + gcol;
      gload_lds16(&sB[wv * 32][0],      gb);
      gload_lds16(&sB[wv * 32 + 16][0], gb + 16 * DM);
    }
    __syncthreads();

    bf16x8 af[4], bfr[4];
#pragma unroll
    for (int t = 0; t < 4; ++t) {
      af[t]  = *(const bf16x8*)&sA[wm + t * 16 + l16][quad * 8];
      bfr[t] = *(const bf16x8*)&sB[wn + t * 16 + l16][quad * 8];
    }
#pragma unroll
    for (int mt = 0; mt < 4; ++mt)
#pragma unroll
      for (int nt = 0; nt < 4; ++nt)
        acc[mt][nt] = __builtin_amdgcn_mfma_f32_16x16x32_bf16(af[mt], bfr[nt], acc[mt][nt], 0, 0, 0);
  }
#pragma unroll
  for (int mt = 0; mt < 4; ++mt) {
#pragma unroll
    for (int r = 0; r < 4; ++r) {
      const size_t m = m0 + wm + mt * 16 + quad * 4 + r;
      OutT* crow = C + m * DM;
#pragma unroll
      for (int nt = 0; nt < 4; ++nt) {
        const float v = acc[mt][nt][r];
        if constexpr (sizeof(OutT) == 2)
          crow[n0 + wn + nt * 16 + l16] = f2bf(v);
        else
          crow[n0 + wn + nt * 16 + l16] = v;
      }
    }
  }
}

__global__ __launch_bounds__(256) void gemm_qkv(
    const short* __restrict__ x,
    const short* __restrict__ Wq, const short* __restrict__ Wk, const short* __restrict__ Wv,
    short* __restrict__ Qb, short* __restrict__ Kb, short* __restrict__ Vb) {
  const short* W = (blockIdx.z == 0) ? Wq : (blockIdx.z == 1) ? Wk : Wv;
  short*       C = (blockIdx.z == 0) ? Qb : (blockIdx.z == 1) ? Kb : Vb;
  gemm_body<short>(x, W, C);
}

__global__ __launch_bounds__(256) void gemm_out(const short* __restrict__ A,
                                                const short* __restrict__ W,
                                                float* __restrict__ C) {
  gemm_body<float>(A, W, C);
}

// ---------------------------------------------------------------------------
// Flash attention, ALiBi, causal — ROUND-5 INNER LOOP VERBATIM.
// Work mapping (only change): blockIdx.x in [0,48):
//   item 0..31 : qt = 16+(item>>1), half = item&1  (split kv range in two)
//   item 32..47: qt = 47-item, full range          (qt 15..0)
// Split blocks write unnormalized bf16 O-partials + fp32 l-partials (valid:
// fixed-offset softmax -> partials combine by simple addition).
// ---------------------------------------------------------------------------
__global__ __launch_bounds__(256) void flash_alibi(const short* __restrict__ Q,
                                                   const short* __restrict__ K,
                                                   const short* __restrict__ V,
                                                   short* __restrict__ O,
                                                   short* __restrict__ Po,
                                                   float* __restrict__ Pl) {
  __shared__ short sK[64][72];             // [key][dim], padded
  __shared__ unsigned int sVt2[64][34];    // [dim][keypair] (round-5 stride)
  __shared__ short sP[4][16][72];          // per-wave P staging (round-5 stride)

  const int tid  = threadIdx.x;
  const int lane = tid & 63, wv = tid >> 6;
  const int quad = lane >> 4, l16 = lane & 15;
  const int item = blockIdx.x;
  int qt, half;
  if (item < 32) { qt = 16 + (item >> 1); half = item & 1; }
  else           { qt = 47 - item;        half = -1; }
  const int n = qt + 1;
  int kts, kte;
  if (half < 0) { kts = 0; kte = n; }
  else { const int n0 = n >> 1; kts = half ? n0 : 0; kte = half ? n : n0; }

  const int h = blockIdx.y, b = blockIdx.z;
  const size_t base = (size_t)b * T_SEQ * DM + (size_t)h * HD;
  const int qi_base = qt * 64;

  // Q fragments (A-layout: m=l16, k=quad*8+j)
  bf16x8 qf[2];
  {
    const int qrow = qi_base + wv * 16 + l16;
    const short* qp = Q + base + (size_t)qrow * DM + quad * 8;
    qf[0] = *(const bf16x8*)(qp);
    qf[1] = *(const bf16x8*)(qp + 32);
  }

  const float slope = exp2f(-0.5f * (float)(h + 1));
  const int srow = tid >> 3;          // K staging row (0..31)
  const int scol = (tid & 7) << 3;    // K staging col
  const int kpair = tid >> 3;         // V staging key pair (0..31)
  const int d0 = (tid & 7) << 3;      // V staging dim group

  f32x4 oacc[4];
#pragma unroll
  for (int c = 0; c < 4; ++c) oacc[c] = (f32x4){0.f, 0.f, 0.f, 0.f};
  float lpart[4] = {0.f, 0.f, 0.f, 0.f};

  for (int kt = kts; kt < kte; ++kt) {
    const int k0 = kt * 64;
    __syncthreads();   // protect sK/sVt2 from previous tile's readers
#pragma unroll
    for (int p = 0; p < 2; ++p) {
      const int row = srow + p * 32;
      *(bf16x8*)&sK[row][scol] = *(const bf16x8*)(K + base + (size_t)(k0 + row) * DM + scol);
    }
    {
      const short* v0 = V + base + (size_t)(k0 + 2 * kpair) * DM + d0;
      bf16x8 va = *(const bf16x8*)v0;
      bf16x8 vb = *(const bf16x8*)(v0 + DM);
#pragma unroll
      for (int e = 0; e < 8; ++e) {
        unsigned w = ((unsigned)(unsigned short)va[e]) |
                     (((unsigned)(unsigned short)vb[e]) << 16);
        sVt2[d0 + e][kpair] = w;
      }
    }
    __syncthreads();

    // S = Q K^T
    f32x4 sacc[4];
#pragma unroll
    for (int c = 0; c < 4; ++c) {
      f32x4 a = (f32x4){0.f, 0.f, 0.f, 0.f};
      a = __builtin_amdgcn_mfma_f32_16x16x32_bf16(
              qf[0], *(const bf16x8*)&sK[c * 16 + l16][quad * 8], a, 0, 0, 0);
      a = __builtin_amdgcn_mfma_f32_16x16x32_bf16(
              qf[1], *(const bf16x8*)&sK[c * 16 + l16][32 + quad * 8], a, 0, 0, 0);
      sacc[c] = a;
    }

    // fixed-offset softmax numerator; masked -> exact 0  (round-5 formulation)
#pragma unroll
    for (int r = 0; r < 4; ++r) {
      const int qi = qi_base + wv * 16 + quad * 4 + r;
#pragma unroll
      for (int c = 0; c < 4; ++c) {
        const int kj = k0 + c * 16 + l16;
        float p = 0.0f;
        if (kj <= qi)
          p = __expf(sacc[c][r] * 0.125f - slope * (float)(qi - kj) - 12.0f);
        lpart[r] += p;
        sP[wv][quad * 4 + r][c * 16 + l16] = f2bf(p);
      }
    }
    // sP is wave-private; in-wave LDS ordering handled by lgkmcnt.

    // O += P V
#pragma unroll
    for (int s = 0; s < 2; ++s) {
      bf16x8 pf = *(const bf16x8*)&sP[wv][l16][s * 32 + quad * 8];
#pragma unroll
      for (int c = 0; c < 4; ++c) {
        const unsigned* vp = &sVt2[c * 16 + l16][s * 16 + quad * 4];
        bf16x4 vlo = *(const bf16x4*)vp;
        bf16x4 vhi = *(const bf16x4*)(vp + 2);
        bf16x8 vf = {vlo[0], vlo[1], vlo[2], vlo[3], vhi[0], vhi[1], vhi[2], vhi[3]};
        oacc[c] = __builtin_amdgcn_mfma_f32_16x16x32_bf16(pf, vf, oacc[c], 0, 0, 0);
      }
    }
  }

  if (half < 0) {
    // full tile: normalize and store bf16 (round-5 epilogue)
#pragma unroll
    for (int r = 0; r < 4; ++r) {
      float l = lpart[r];
#pragma unroll
      for (int off = 1; off < 16; off <<= 1) l += __shfl_xor(l, off);
      const float inv = 1.0f / fmaxf(l, 1e-37f);
      const int qi = qi_base + wv * 16 + quad * 4 + r;
      short* orow = O + base + (size_t)qi * DM;
#pragma unroll
      for (int c = 0; c < 4; ++c)
        orow[c * 16 + l16] = f2bf(oacc[c][r] * inv);
    }
  } else {
    // split half: store unnormalized O partial (bf16) + l partial (fp32)
    const int pidx = (((b * NH + h) * 16) + (qt - 16)) * 2 + half;
    short* po = Po + (size_t)pidx * 4096;   // [64 rows][64 dims]
    float* pl = Pl + (size_t)pidx * 64;
#pragma unroll
    for (int r = 0; r < 4; ++r) {
      float l = lpart[r];
#pragma unroll
      for (int off = 1; off < 16; off <<= 1) l += __shfl_xor(l, off);
      const int row = wv * 16 + quad * 4 + r;
      if (l16 == 0) pl[row] = l;
#pragma unroll
      for (int c = 0; c < 4; ++c)
        po[row * 64 + c * 16 + l16] = f2bf(oacc[c][r]);
    }
  }
}

// ---------------------------------------------------------------------------
// Combine: O = (O0+O1)/(l0+l1) -> bf16 for the split (long) rows.
// 32768 rows x 64 dims; 32 rows/block, 8 threads/row.
// ---------------------------------------------------------------------------
__global__ __launch_bounds__(256) void combine(const short* __restrict__ Po,
                                               const float* __restrict__ Pl,
                                               short* __restrict__ O) {
  const int g = blockIdx.x * 32 + (threadIdx.x >> 3);   // 0..32767
  const int d = (threadIdx.x & 7) << 3;
  const int row = g & 63;
  const int lt  = (g >> 6) & 15;
  const int h   = (g >> 10) & 15;
  const int b   = g >> 14;
  const int pbase = (((b * NH + h) * 16) + lt) * 2;
  const short* p0 = Po + (size_t)(pbase + 0) * 4096 + row * 64 + d;
  const short* p1 = Po + (size_t)(pbase + 1) * 4096 + row * 64 + d;
  const float l = Pl[(pbase + 0) * 64 + row] + Pl[(pbase + 1) * 64 + row];
  const float inv = 1.0f / fmaxf(l, 1e-37f);
  bf16x8 a = *(const bf16x8*)p0;
  bf16x8 bb = *(const bf16x8*)p1;
  const int qi = (16 + lt) * 64 + row;
  short* orow = O + (size_t)b * T_SEQ * DM + (size_t)qi * DM + h * HD + d;
  bf16x8 o;
#pragma unroll
  for (int e = 0; e < 8; ++e) o[e] = f2bf((bf2f(a[e]) + bf2f(bb[e])) * inv);
  *(bf16x8*)orow = o;
}

// ---------------------------------------------------------------------------
extern "C" void kernel_launch(void* const* d_in, const int* in_sizes, int n_in,
                              void* d_out, int out_size, void* d_ws, size_t ws_size,
                              hipStream_t stream) {
  float* out = (float*)d_out;   // fp32 output

  short* ws = (short*)d_ws;
  const size_t plane = (size_t)NROW * DM;   // 4M elements
  const size_t wsz   = (size_t)DM * DM;     // 1M elements
  short* xb  = ws;
  short* Wqb = xb + plane;
  short* Wkb = Wqb + wsz;
  short* Wvb = Wkb + wsz;
  short* Wob = Wvb + wsz;
  short* Qb  = Wob + wsz;
  short* Kb  = Qb + plane;
  short* Vb  = Kb + plane;
  short* Ab  = Vb + plane;
  short* Po  = Ab + plane;                  // 1024 slabs * 4096 bf16 = 8 MB
  float* Pl  = (float*)(Po + (size_t)1024 * 4096);   // 256 KB

  dim3 blk(256);
  convert_all<<<8192, blk, 0, stream>>>(
      (const float*)d_in[0], (const float*)d_in[1], (const float*)d_in[2],
      (const float*)d_in[3], (const float*)d_in[4],
      xb, Wqb, Wkb, Wvb, Wob);

  gemm_qkv<<<dim3(NROW / 128, DM / 128, 3), blk, 0, stream>>>(xb, Wqb, Wkb, Wvb, Qb, Kb, Vb);
  flash_alibi<<<dim3(48, NH, 2), blk, 0, stream>>>(Qb, Kb, Vb, Ab, Po, Pl);
  combine<<<1024, blk, 0, stream>>>(Po, Pl, Ab);
  gemm_out<<<dim3(NROW / 128, DM / 128, 1), blk, 0, stream>>>(Ab, Wob, out);
}